// Round 5
// baseline (337.407 us; speedup 1.0000x reference)
//
#include <hip/hip_runtime.h>
#include <hip/hip_bf16.h>

// Problem constants
#define BATCH   2
#define LSEQ    2048
#define DMODEL  1024
#define DINNER  2048
#define NST     16

// Chunked scan parameters
#define LC      64
#define NCHUNK  (LSEQ / LC)   // 32

#define LOG2E 1.4426950408889634f

typedef __bf16 bf16x8 __attribute__((ext_vector_type(8)));
typedef float  f32x4  __attribute__((ext_vector_type(4)));

// float -> bf16 round-to-nearest-even (inputs are finite; skip NaN path)
__device__ __forceinline__ unsigned short f2bf(float f) {
  unsigned int u = __float_as_uint(f);
  return (unsigned short)((u + 0x7FFFu + ((u >> 16) & 1u)) >> 16);
}

__device__ __forceinline__ void async_copy16(const void* g, void* l) {
  __builtin_amdgcn_global_load_lds((__attribute__((address_space(1))) void*)g,
                                   (__attribute__((address_space(3))) void*)l,
                                   16, 0, 0);
}

// ---------------------------------------------------------------------------
// f32 -> bf16 conversion, 4 elements/thread
// ---------------------------------------------------------------------------
__global__ __launch_bounds__(256) void cvt_bf16(const float4* __restrict__ in,
                                                ushort4* __restrict__ o, int n4) {
  int i = blockIdx.x * 256 + threadIdx.x;
  if (i >= n4) return;
  float4 v = in[i];
  ushort4 r;
  r.x = f2bf(v.x); r.y = f2bf(v.y); r.z = f2bf(v.z); r.w = f2bf(v.w);
  o[i] = r;
}

// ---------------------------------------------------------------------------
// bf16 NT GEMM (m97 structure): C[m][n] = sum_k A[m][k]*B[n][k], C fp32.
// ---------------------------------------------------------------------------
template<int N, int K>
__global__ __launch_bounds__(256, 2) void gemm_bf16(const unsigned short* __restrict__ A,
                                                    const unsigned short* __restrict__ B,
                                                    float* __restrict__ C) {
  __shared__ unsigned short As[128][32];
  __shared__ unsigned short Bs[128][32];
  const int tid  = threadIdx.x;
  const int wave = tid >> 6;
  const int lane = tid & 63;
  const int row0 = blockIdx.y * 128;
  const int col0 = blockIdx.x * 128;
  const int wr   = (wave >> 1) * 64;
  const int wc   = (wave & 1)  * 64;
  const int fr   = lane & 15;
  const int fq   = lane >> 4;

  f32x4 acc[4][4] = {};

  const int srow = tid >> 2;
  const int skof = (tid & 3) * 8;
  const unsigned short* gA = A + (size_t)(row0 + srow) * K + skof;
  const unsigned short* gB = B + (size_t)(col0 + srow) * K + skof;
  char* lA = (char*)&As[0][0] + wave * 1024;
  char* lB = (char*)&Bs[0][0] + wave * 1024;

  for (int k0 = 0; k0 < K; k0 += 32) {
    async_copy16(gA + k0,          lA);
    async_copy16(gA + k0 + 64 * K, lA + 4096);
    async_copy16(gB + k0,          lB);
    async_copy16(gB + k0 + 64 * K, lB + 4096);
    __syncthreads();

    bf16x8 af[4], bfr[4];
    #pragma unroll
    for (int i = 0; i < 4; ++i) {
      af[i]  = *(const bf16x8*)((const char*)&As[0][0] + (wr + i * 16 + fr) * 64 + fq * 16);
      bfr[i] = *(const bf16x8*)((const char*)&Bs[0][0] + (wc + i * 16 + fr) * 64 + fq * 16);
    }
    #pragma unroll
    for (int i = 0; i < 4; ++i)
      #pragma unroll
      for (int j = 0; j < 4; ++j)
        acc[i][j] = __builtin_amdgcn_mfma_f32_16x16x32_bf16(af[i], bfr[j], acc[i][j], 0, 0, 0);
    __syncthreads();
  }

  #pragma unroll
  for (int i = 0; i < 4; ++i)
    #pragma unroll
    for (int j = 0; j < 4; ++j) {
      int row = row0 + wr + i * 16 + fq * 4;
      int col = col0 + wc + j * 16 + fr;
      #pragma unroll
      for (int r = 0; r < 4; ++r)
        C[(size_t)(row + r) * N + col] = acc[i][j][r];
    }
}

// ---------------------------------------------------------------------------
// Causal depthwise conv1d(K=4) + bias + SiLU, 4 d-channels per thread.
// ---------------------------------------------------------------------------
__global__ __launch_bounds__(256) void conv_kernel(const float* __restrict__ xz,
                                                   const float* __restrict__ cw,
                                                   const float* __restrict__ cb,
                                                   float* __restrict__ u) {
  size_t i4 = (size_t)blockIdx.x * 256 + threadIdx.x;  // float4 index over B*L*D/4
  int d4 = (int)(i4 & (DINNER / 4 - 1));
  int t  = (int)((i4 >> 9) & (LSEQ - 1));
  int d  = d4 * 4;

  float4 w0 = *(const float4*)(cw + (d + 0) * 4);
  float4 w1 = *(const float4*)(cw + (d + 1) * 4);
  float4 w2 = *(const float4*)(cw + (d + 2) * 4);
  float4 w3 = *(const float4*)(cw + (d + 3) * 4);
  float4 bias = *(const float4*)(cb + d);

  size_t base = i4 * 8 - (size_t)d;  // row*2*DINNER + d, row = b*L+t
  const float4 zero = make_float4(0.f, 0.f, 0.f, 0.f);
  float4 x0 =          *(const float4*)(xz + base);                          // t
  float4 x1 = (t >= 1) ? *(const float4*)(xz + base - 1 * (2 * DINNER)) : zero;
  float4 x2 = (t >= 2) ? *(const float4*)(xz + base - 2 * (2 * DINNER)) : zero;
  float4 x3 = (t >= 3) ? *(const float4*)(xz + base - 3 * (2 * DINNER)) : zero;

  float4 s;
  s.x = bias.x + w0.x * x3.x + w0.y * x2.x + w0.z * x1.x + w0.w * x0.x;
  s.y = bias.y + w1.x * x3.y + w1.y * x2.y + w1.z * x1.y + w1.w * x0.y;
  s.z = bias.z + w2.x * x3.z + w2.y * x2.z + w2.z * x1.z + w2.w * x0.z;
  s.w = bias.w + w3.x * x3.w + w3.y * x2.w + w3.z * x1.w + w3.w * x0.w;

  float4 r;
  r.x = s.x / (1.0f + __expf(-s.x));
  r.y = s.y / (1.0f + __expf(-s.y));
  r.z = s.z / (1.0f + __expf(-s.z));
  r.w = s.w / (1.0f + __expf(-s.w));
  *(float4*)(u + i4 * 4) = r;
}

// ---------------------------------------------------------------------------
// x_dbl: one wave per 2 rows (4 waves/block, 512 blocks).
// Each lane: 8 float4 k-slices per row; 33 outputs accumulated in regs;
// 64-lane butterfly; lane0/lane1 write bc; all lanes write softplus-delta.
// ---------------------------------------------------------------------------
__global__ __launch_bounds__(256) void xdbl_kernel(const float* __restrict__ u,
                                                   const float* __restrict__ Wx,
                                                   const float* __restrict__ Wdt,
                                                   const float* __restrict__ bdt,
                                                   float* __restrict__ xz,
                                                   float* __restrict__ bc) {
  const int tid  = threadIdx.x;
  const int wave = tid >> 6;
  const int lane = tid & 63;
  const int rowA = blockIdx.x * 8 + wave * 2;
  const int rowB = rowA + 1;

  float accA[33], accB[33];
  #pragma unroll
  for (int e = 0; e < 33; ++e) { accA[e] = 0.0f; accB[e] = 0.0f; }

  const float* uA = u + (size_t)rowA * DINNER;
  const float* uB = u + (size_t)rowB * DINNER;

  #pragma unroll
  for (int i = 0; i < 8; ++i) {
    const int k = (lane + 64 * i) * 4;
    float4 ua = *(const float4*)(uA + k);
    float4 ub = *(const float4*)(uB + k);
    #pragma unroll
    for (int e = 0; e < 33; ++e) {
      float4 w = *(const float4*)(Wx + (size_t)e * DINNER + k);
      accA[e] = fmaf(ua.x, w.x, fmaf(ua.y, w.y, fmaf(ua.z, w.z, fmaf(ua.w, w.w, accA[e]))));
      accB[e] = fmaf(ub.x, w.x, fmaf(ub.y, w.y, fmaf(ub.z, w.z, fmaf(ub.w, w.w, accB[e]))));
    }
  }

  #pragma unroll
  for (int e = 0; e < 33; ++e) {
    #pragma unroll
    for (int m = 1; m < 64; m <<= 1) {
      accA[e] += __shfl_xor(accA[e], m);
      accB[e] += __shfl_xor(accB[e], m);
    }
  }

  if (lane == 0) {
    #pragma unroll
    for (int e = 1; e < 33; ++e) bc[(size_t)rowA * 32 + e - 1] = accA[e];
  } else if (lane == 1) {
    #pragma unroll
    for (int e = 1; e < 33; ++e) bc[(size_t)rowB * 32 + e - 1] = accB[e];
  }

  const float dltA = accA[0];
  const float dltB = accB[0];
  #pragma unroll
  for (int i = 0; i < 8; ++i) {
    const int d = (lane + 64 * i) * 4;
    float4 wd = *(const float4*)(Wdt + d);
    float4 bd = *(const float4*)(bdt + d);
    float4 ra, rb;
    {
      float xa, xb;
      xa = fmaf(dltA, wd.x, bd.x); xb = fmaf(dltB, wd.x, bd.x);
      ra.x = fmaxf(xa, 0.f) + log1pf(__expf(-fabsf(xa)));
      rb.x = fmaxf(xb, 0.f) + log1pf(__expf(-fabsf(xb)));
      xa = fmaf(dltA, wd.y, bd.y); xb = fmaf(dltB, wd.y, bd.y);
      ra.y = fmaxf(xa, 0.f) + log1pf(__expf(-fabsf(xa)));
      rb.y = fmaxf(xb, 0.f) + log1pf(__expf(-fabsf(xb)));
      xa = fmaf(dltA, wd.z, bd.z); xb = fmaf(dltB, wd.z, bd.z);
      ra.z = fmaxf(xa, 0.f) + log1pf(__expf(-fabsf(xa)));
      rb.z = fmaxf(xb, 0.f) + log1pf(__expf(-fabsf(xb)));
      xa = fmaf(dltA, wd.w, bd.w); xb = fmaf(dltB, wd.w, bd.w);
      ra.w = fmaxf(xa, 0.f) + log1pf(__expf(-fabsf(xa)));
      rb.w = fmaxf(xb, 0.f) + log1pf(__expf(-fabsf(xb)));
    }
    *(float4*)(xz + (size_t)rowA * (2 * DINNER) + d) = ra;
    *(float4*)(xz + (size_t)rowB * (2 * DINNER) + d) = rb;
  }
}

// ---------------------------------------------------------------------------
// Chunked scan, phase A. Lane = one (b, d, chunk); all 16 states in regs.
// ---------------------------------------------------------------------------
__global__ __launch_bounds__(256) void scanA(const float* __restrict__ u,
                                             const float* __restrict__ xz,
                                             const float* __restrict__ bc,
                                             const float* __restrict__ Amat,
                                             float* __restrict__ Pbuf,
                                             float* __restrict__ Wbuf) {
  const int tid  = threadIdx.x;
  const int dblk = blockIdx.x & 7;
  const int c    = (blockIdx.x >> 3) & (NCHUNK - 1);
  const int b    = blockIdx.x >> 8;
  const int d    = dblk * 256 + tid;
  const int t0   = c * LC;

  float A2[16];
  #pragma unroll
  for (int i = 0; i < 4; ++i) {
    float4 v = *(const float4*)(Amat + (size_t)d * 16 + i * 4);
    A2[i*4+0] = v.x * LOG2E; A2[i*4+1] = v.y * LOG2E;
    A2[i*4+2] = v.z * LOG2E; A2[i*4+3] = v.w * LOG2E;
  }
  float h[16];
  #pragma unroll
  for (int n = 0; n < 16; ++n) h[n] = 0.0f;
  float S = 0.0f;

  const float* bcb = bc + ((size_t)b * LSEQ + t0) * 32;
  size_t gu = ((size_t)b * LSEQ + t0) * DINNER + d;
  size_t gx = ((size_t)b * LSEQ + t0) * (2 * DINNER) + d;

  float u_c = u[gu], dl_c = xz[gx];
  for (int tt = 0; tt < LC; ++tt) {
    float u_n  = u [gu + DINNER];
    float dl_n = xz[gx + 2 * DINNER];
    gu += DINNER; gx += 2 * DINNER;
    float4 B0 = *(const float4*)(bcb + tt * 32 + 0);
    float4 B1 = *(const float4*)(bcb + tt * 32 + 4);
    float4 B2 = *(const float4*)(bcb + tt * 32 + 8);
    float4 B3 = *(const float4*)(bcb + tt * 32 + 12);
    float Bv[16] = {B0.x,B0.y,B0.z,B0.w, B1.x,B1.y,B1.z,B1.w,
                    B2.x,B2.y,B2.z,B2.w, B3.x,B3.y,B3.z,B3.w};
    S += dl_c;
    float dlu = dl_c * u_c;
    #pragma unroll
    for (int n = 0; n < 16; ++n) {
      float ab = exp2f(dl_c * A2[n]);
      h[n] = fmaf(ab, h[n], dlu * Bv[n]);
    }
    u_c = u_n; dl_c = dl_n;
  }

  size_t o = ((size_t)(b * DINNER + d) * NCHUNK + c) * 16;
  float P[16];
  #pragma unroll
  for (int n = 0; n < 16; ++n) P[n] = exp2f(A2[n] * S);
  #pragma unroll
  for (int i = 0; i < 4; ++i) {
    *(float4*)(Pbuf + o + i * 4) = make_float4(P[i*4], P[i*4+1], P[i*4+2], P[i*4+3]);
    *(float4*)(Wbuf + o + i * 4) = make_float4(h[i*4], h[i*4+1], h[i*4+2], h[i*4+3]);
  }
}

// ---------------------------------------------------------------------------
// Phase B: combine 32 chunk summaries per (b,d,n) lane; Hin over Pbuf.
// ---------------------------------------------------------------------------
__global__ __launch_bounds__(256) void scanB(float* __restrict__ Pbuf,
                                             const float* __restrict__ Wbuf) {
  const int lane_id = blockIdx.x * 256 + threadIdx.x;
  const int gc = lane_id >> 4;
  const int n  = lane_id & 15;
  const size_t base = (size_t)gc * NCHUNK * 16 + n;
  float P[NCHUNK], W[NCHUNK];
  #pragma unroll
  for (int c = 0; c < NCHUNK; ++c) {
    P[c] = Pbuf[base + (size_t)c * 16];
    W[c] = Wbuf[base + (size_t)c * 16];
  }
  float h = 0.0f;
  #pragma unroll
  for (int c = 0; c < NCHUNK; ++c) {
    float hin = h;
    h = P[c] * h + W[c];
    Pbuf[base + (size_t)c * 16] = hin;
  }
}

// ---------------------------------------------------------------------------
// Phase C: lane = one (b, d, chunk); rescan from Hin, y = sum_n h_n C_n,
// SiLU(z) gate, write y (fp32) in place over u.
// ---------------------------------------------------------------------------
__global__ __launch_bounds__(256) void scanC(float* __restrict__ u,
                                             const float* __restrict__ xz,
                                             const float* __restrict__ bc,
                                             const float* __restrict__ Amat,
                                             const float* __restrict__ Hin) {
  const int tid  = threadIdx.x;
  const int dblk = blockIdx.x & 7;
  const int c    = (blockIdx.x >> 3) & (NCHUNK - 1);
  const int b    = blockIdx.x >> 8;
  const int d    = dblk * 256 + tid;
  const int t0   = c * LC;

  float A2[16];
  #pragma unroll
  for (int i = 0; i < 4; ++i) {
    float4 v = *(const float4*)(Amat + (size_t)d * 16 + i * 4);
    A2[i*4+0] = v.x * LOG2E; A2[i*4+1] = v.y * LOG2E;
    A2[i*4+2] = v.z * LOG2E; A2[i*4+3] = v.w * LOG2E;
  }
  const size_t o = ((size_t)(b * DINNER + d) * NCHUNK + c) * 16;
  float h[16];
  #pragma unroll
  for (int i = 0; i < 4; ++i) {
    float4 v = *(const float4*)(Hin + o + i * 4);
    h[i*4+0] = v.x; h[i*4+1] = v.y; h[i*4+2] = v.z; h[i*4+3] = v.w;
  }

  const float* bcb = bc + ((size_t)b * LSEQ + t0) * 32;
  size_t gu = ((size_t)b * LSEQ + t0) * DINNER + d;
  size_t gx = ((size_t)b * LSEQ + t0) * (2 * DINNER) + d;

  float u_c = u[gu], dl_c = xz[gx], z_c = xz[gx + DINNER];
  for (int tt = 0; tt < LC; ++tt) {
    size_t cu = gu;
    gu += DINNER; gx += 2 * DINNER;
    float u_n  = u [gu];
    float dl_n = xz[gx];
    float z_n  = xz[gx + DINNER];
    float4 B0 = *(const float4*)(bcb + tt * 32 + 0);
    float4 B1 = *(const float4*)(bcb + tt * 32 + 4);
    float4 B2 = *(const float4*)(bcb + tt * 32 + 8);
    float4 B3 = *(const float4*)(bcb + tt * 32 + 12);
    float4 C0 = *(const float4*)(bcb + tt * 32 + 16);
    float4 C1 = *(const float4*)(bcb + tt * 32 + 20);
    float4 C2 = *(const float4*)(bcb + tt * 32 + 24);
    float4 C3 = *(const float4*)(bcb + tt * 32 + 28);
    float Bv[16] = {B0.x,B0.y,B0.z,B0.w, B1.x,B1.y,B1.z,B1.w,
                    B2.x,B2.y,B2.z,B2.w, B3.x,B3.y,B3.z,B3.w};
    float Cv[16] = {C0.x,C0.y,C0.z,C0.w, C1.x,C1.y,C1.z,C1.w,
                    C2.x,C2.y,C2.z,C2.w, C3.x,C3.y,C3.z,C3.w};
    float dlu = dl_c * u_c;
    float y = 0.0f;
    #pragma unroll
    for (int n = 0; n < 16; ++n) {
      float ab = exp2f(dl_c * A2[n]);
      h[n] = fmaf(ab, h[n], dlu * Bv[n]);
      y = fmaf(h[n], Cv[n], y);
    }
    float sig = 1.0f / (1.0f + __expf(-z_c));
    u[cu] = y * z_c * sig;
    u_c = u_n; dl_c = dl_n; z_c = z_n;
  }
}

// ---------------------------------------------------------------------------
extern "C" void kernel_launch(void* const* d_in, const int* in_sizes, int n_in,
                              void* d_out, int out_size, void* d_ws, size_t ws_size,
                              hipStream_t stream) {
  const float* x      = (const float*)d_in[0];
  const float* W_in   = (const float*)d_in[1];
  const float* conv_w = (const float*)d_in[2];
  const float* conv_b = (const float*)d_in[3];
  const float* A      = (const float*)d_in[4];
  const float* W_x    = (const float*)d_in[5];
  const float* W_dt   = (const float*)d_in[6];
  const float* b_dt   = (const float*)d_in[7];
  const float* W_out  = (const float*)d_in[8];
  float* out = (float*)d_out;

  float* ws = (float*)d_ws;
  float* xz = ws;                                        // (B*L, 4096)   64 MB
  float* u  = xz + (size_t)BATCH * LSEQ * 2 * DINNER;    // (B*L, 2048)   32 MB
  float* bc = u  + (size_t)BATCH * LSEQ * DINNER;        // (B*L, 32)    0.5 MB
  float* Pb = bc + (size_t)BATCH * LSEQ * 32;            // 2M floats      8 MB
  float* Wb = Pb + (size_t)BATCH * DINNER * NCHUNK * 16; // 2M floats      8 MB

  const int ML = BATCH * LSEQ;  // 4096

  // bf16 aliases (regions dead at time of use)
  unsigned short* x_bf    = (unsigned short*)Pb;   // dead until scanA
  unsigned short* win_bf  = (unsigned short*)Wb;   // dead until scanA
  unsigned short* y_bf    = (unsigned short*)Pb;   // spans Pb+Wb, dead after scanC
  unsigned short* wout_bf = (unsigned short*)xz;   // xz dead after scanC

  // 0) convert in_proj operands to bf16
  cvt_bf16<<<(ML * DMODEL / 4) / 256, 256, 0, stream>>>((const float4*)x,    (ushort4*)x_bf,   ML * DMODEL / 4);
  cvt_bf16<<<(2 * DINNER * DMODEL / 4) / 256, 256, 0, stream>>>((const float4*)W_in, (ushort4*)win_bf, 2 * DINNER * DMODEL / 4);
  // 1) in_proj (bf16 MFMA)
  gemm_bf16<2 * DINNER, DMODEL><<<dim3((2 * DINNER) / 128, ML / 128), 256, 0, stream>>>(x_bf, win_bf, xz);
  // 2) conv + silu
  conv_kernel<<<(ML * DINNER / 4) / 256, 256, 0, stream>>>(xz, conv_w, conv_b, u);
  // 3) x_dbl
  xdbl_kernel<<<ML / 8, 256, 0, stream>>>(u, W_x, W_dt, b_dt, xz, bc);
  // 4) chunked selective scan (register-state lanes)
  scanA<<<BATCH * NCHUNK * 8, 256, 0, stream>>>(u, xz, bc, A, Pb, Wb);
  scanB<<<(BATCH * DINNER * NST) / 256, 256, 0, stream>>>(Pb, Wb);
  scanC<<<BATCH * NCHUNK * 8, 256, 0, stream>>>(u, xz, bc, A, Pb);
  // 5) convert out_proj operands, then out_proj (bf16 MFMA)
  cvt_bf16<<<(ML * DINNER / 4) / 256, 256, 0, stream>>>((const float4*)u,     (ushort4*)y_bf,    ML * DINNER / 4);
  cvt_bf16<<<(DMODEL * DINNER / 4) / 256, 256, 0, stream>>>((const float4*)W_out, (ushort4*)wout_bf, DMODEL * DINNER / 4);
  gemm_bf16<DMODEL, DINNER><<<dim3(DMODEL / 128, ML / 128), 256, 0, stream>>>(y_bf, wout_bf, out);
}

// Round 6
// 318.304 us; speedup vs baseline: 1.0600x; 1.0600x over previous
//
#include <hip/hip_runtime.h>
#include <hip/hip_bf16.h>

// Problem constants
#define BATCH   2
#define LSEQ    2048
#define DMODEL  1024
#define DINNER  2048
#define NST     16

// Chunked scan parameters
#define LC      64
#define NCHUNK  (LSEQ / LC)   // 32

#define LOG2E 1.4426950408889634f

typedef __bf16 bf16x8 __attribute__((ext_vector_type(8)));
typedef float  f32x4  __attribute__((ext_vector_type(4)));

// float -> bf16 round-to-nearest-even (inputs are finite; skip NaN path)
__device__ __forceinline__ unsigned short f2bf(float f) {
  unsigned int u = __float_as_uint(f);
  return (unsigned short)((u + 0x7FFFu + ((u >> 16) & 1u)) >> 16);
}

__device__ __forceinline__ void async_copy16(const void* g, void* l) {
  __builtin_amdgcn_global_load_lds((__attribute__((address_space(1))) void*)g,
                                   (__attribute__((address_space(3))) void*)l,
                                   16, 0, 0);
}

// ---------------------------------------------------------------------------
// f32 -> bf16 conversion, 4 elements/thread
// ---------------------------------------------------------------------------
__global__ __launch_bounds__(256) void cvt_bf16(const float4* __restrict__ in,
                                                ushort4* __restrict__ o, int n4) {
  int i = blockIdx.x * 256 + threadIdx.x;
  if (i >= n4) return;
  float4 v = in[i];
  ushort4 r;
  r.x = f2bf(v.x); r.y = f2bf(v.y); r.z = f2bf(v.z); r.w = f2bf(v.w);
  o[i] = r;
}

// ---------------------------------------------------------------------------
// bf16 NT GEMM (m97 structure): C[m][n] = sum_k A[m][k]*B[n][k], C fp32.
// ---------------------------------------------------------------------------
template<int N, int K>
__global__ __launch_bounds__(256, 2) void gemm_bf16(const unsigned short* __restrict__ A,
                                                    const unsigned short* __restrict__ B,
                                                    float* __restrict__ C) {
  __shared__ unsigned short As[128][32];
  __shared__ unsigned short Bs[128][32];
  const int tid  = threadIdx.x;
  const int wave = tid >> 6;
  const int lane = tid & 63;
  const int row0 = blockIdx.y * 128;
  const int col0 = blockIdx.x * 128;
  const int wr   = (wave >> 1) * 64;
  const int wc   = (wave & 1)  * 64;
  const int fr   = lane & 15;
  const int fq   = lane >> 4;

  f32x4 acc[4][4] = {};

  const int srow = tid >> 2;
  const int skof = (tid & 3) * 8;
  const unsigned short* gA = A + (size_t)(row0 + srow) * K + skof;
  const unsigned short* gB = B + (size_t)(col0 + srow) * K + skof;
  char* lA = (char*)&As[0][0] + wave * 1024;
  char* lB = (char*)&Bs[0][0] + wave * 1024;

  for (int k0 = 0; k0 < K; k0 += 32) {
    async_copy16(gA + k0,          lA);
    async_copy16(gA + k0 + 64 * K, lA + 4096);
    async_copy16(gB + k0,          lB);
    async_copy16(gB + k0 + 64 * K, lB + 4096);
    __syncthreads();

    bf16x8 af[4], bfr[4];
    #pragma unroll
    for (int i = 0; i < 4; ++i) {
      af[i]  = *(const bf16x8*)((const char*)&As[0][0] + (wr + i * 16 + fr) * 64 + fq * 16);
      bfr[i] = *(const bf16x8*)((const char*)&Bs[0][0] + (wc + i * 16 + fr) * 64 + fq * 16);
    }
    #pragma unroll
    for (int i = 0; i < 4; ++i)
      #pragma unroll
      for (int j = 0; j < 4; ++j)
        acc[i][j] = __builtin_amdgcn_mfma_f32_16x16x32_bf16(af[i], bfr[j], acc[i][j], 0, 0, 0);
    __syncthreads();
  }

  #pragma unroll
  for (int i = 0; i < 4; ++i)
    #pragma unroll
    for (int j = 0; j < 4; ++j) {
      int row = row0 + wr + i * 16 + fq * 4;
      int col = col0 + wc + j * 16 + fr;
      #pragma unroll
      for (int r = 0; r < 4; ++r)
        C[(size_t)(row + r) * N + col] = acc[i][j][r];
    }
}

// ---------------------------------------------------------------------------
// Causal depthwise conv1d(K=4) + bias + SiLU, 4 d-channels per thread.
// ---------------------------------------------------------------------------
__global__ __launch_bounds__(256) void conv_kernel(const float* __restrict__ xz,
                                                   const float* __restrict__ cw,
                                                   const float* __restrict__ cb,
                                                   float* __restrict__ u) {
  size_t i4 = (size_t)blockIdx.x * 256 + threadIdx.x;  // float4 index over B*L*D/4
  int d4 = (int)(i4 & (DINNER / 4 - 1));
  int t  = (int)((i4 >> 9) & (LSEQ - 1));
  int d  = d4 * 4;

  float4 w0 = *(const float4*)(cw + (d + 0) * 4);
  float4 w1 = *(const float4*)(cw + (d + 1) * 4);
  float4 w2 = *(const float4*)(cw + (d + 2) * 4);
  float4 w3 = *(const float4*)(cw + (d + 3) * 4);
  float4 bias = *(const float4*)(cb + d);

  size_t base = i4 * 8 - (size_t)d;  // row*2*DINNER + d, row = b*L+t
  const float4 zero = make_float4(0.f, 0.f, 0.f, 0.f);
  float4 x0 =          *(const float4*)(xz + base);
  float4 x1 = (t >= 1) ? *(const float4*)(xz + base - 1 * (2 * DINNER)) : zero;
  float4 x2 = (t >= 2) ? *(const float4*)(xz + base - 2 * (2 * DINNER)) : zero;
  float4 x3 = (t >= 3) ? *(const float4*)(xz + base - 3 * (2 * DINNER)) : zero;

  float4 s;
  s.x = bias.x + w0.x * x3.x + w0.y * x2.x + w0.z * x1.x + w0.w * x0.x;
  s.y = bias.y + w1.x * x3.y + w1.y * x2.y + w1.z * x1.y + w1.w * x0.y;
  s.z = bias.z + w2.x * x3.z + w2.y * x2.z + w2.z * x1.z + w2.w * x0.z;
  s.w = bias.w + w3.x * x3.w + w3.y * x2.w + w3.z * x1.w + w3.w * x0.w;

  float4 r;
  r.x = s.x / (1.0f + __expf(-s.x));
  r.y = s.y / (1.0f + __expf(-s.y));
  r.z = s.z / (1.0f + __expf(-s.z));
  r.w = s.w / (1.0f + __expf(-s.w));
  *(float4*)(u + i4 * 4) = r;
}

// ---------------------------------------------------------------------------
// x_dbl: one wave per 2 rows (4 waves/block -> 8 rows/block, 512 blocks).
// Wx staged in LDS per 256-wide k-tile via global_load_lds; each lane owns
// one float4 k-slice per row per tile; 66 reg accumulators; 64-lane
// butterfly; bc + softplus-delta epilogue. fp32-exact.
// ---------------------------------------------------------------------------
__global__ __launch_bounds__(256) void xdbl_kernel(const float* __restrict__ u,
                                                   const float* __restrict__ Wx,
                                                   const float* __restrict__ Wdt,
                                                   const float* __restrict__ bdt,
                                                   float* __restrict__ xz,
                                                   float* __restrict__ bc) {
  __shared__ float sW[33 * 256];   // 33.8 KB: Wx tile [e=0..32][k0..k0+255]
  const int tid  = threadIdx.x;
  const int wave = tid >> 6;
  const int lane = tid & 63;
  const int rowA = blockIdx.x * 8 + wave * 2;
  const int rowB = rowA + 1;

  float accA[33], accB[33];
  #pragma unroll
  for (int e = 0; e < 33; ++e) { accA[e] = 0.0f; accB[e] = 0.0f; }

  const float* uA = u + (size_t)rowA * DINNER;
  const float* uB = u + (size_t)rowB * DINNER;

  for (int k0 = 0; k0 < DINNER; k0 += 256) {
    // stage 33x256 fp32 tile: transfer unit = float4; 2112 transfers total.
    // LDS dest must be the wave-uniform base (HW adds lane*16).
    #pragma unroll
    for (int j = 0; j < 9; ++j) {
      int i = j * 256 + wave * 64 + lane;   // transfer index
      if (i < 33 * 64) {                    // wave-uniform predicate
        int e = i >> 6;
        int c = (i & 63) * 4;
        async_copy16(Wx + (size_t)e * DINNER + k0 + c,
                     (char*)sW + (size_t)(j * 256 + wave * 64) * 16);
      }
    }
    __syncthreads();   // drains vmcnt: tile resident

    float4 a4 = *(const float4*)(uA + k0 + lane * 4);
    float4 b4 = *(const float4*)(uB + k0 + lane * 4);
    #pragma unroll
    for (int e = 0; e < 33; ++e) {
      float4 w = *(const float4*)(sW + e * 256 + lane * 4);  // ds_read_b128
      accA[e] = fmaf(a4.x, w.x, fmaf(a4.y, w.y, fmaf(a4.z, w.z, fmaf(a4.w, w.w, accA[e]))));
      accB[e] = fmaf(b4.x, w.x, fmaf(b4.y, w.y, fmaf(b4.z, w.z, fmaf(b4.w, w.w, accB[e]))));
    }
    __syncthreads();   // reads done before next stage overwrites
  }

  // 64-lane butterfly: every lane ends with the full row sums
  #pragma unroll
  for (int e = 0; e < 33; ++e) {
    #pragma unroll
    for (int m = 1; m < 64; m <<= 1) {
      accA[e] += __shfl_xor(accA[e], m);
      accB[e] += __shfl_xor(accB[e], m);
    }
  }

  if (lane == 0) {
    #pragma unroll
    for (int e = 1; e < 33; ++e) bc[(size_t)rowA * 32 + e - 1] = accA[e];
  } else if (lane == 1) {
    #pragma unroll
    for (int e = 1; e < 33; ++e) bc[(size_t)rowB * 32 + e - 1] = accB[e];
  }

  const float dltA = accA[0];
  const float dltB = accB[0];
  #pragma unroll
  for (int i = 0; i < 8; ++i) {
    const int d = (i * 64 + lane) * 4;
    float4 wd = *(const float4*)(Wdt + d);
    float4 bd = *(const float4*)(bdt + d);
    float4 ra, rb;
    float xa, xb;
    xa = fmaf(dltA, wd.x, bd.x); xb = fmaf(dltB, wd.x, bd.x);
    ra.x = fmaxf(xa, 0.f) + log1pf(__expf(-fabsf(xa)));
    rb.x = fmaxf(xb, 0.f) + log1pf(__expf(-fabsf(xb)));
    xa = fmaf(dltA, wd.y, bd.y); xb = fmaf(dltB, wd.y, bd.y);
    ra.y = fmaxf(xa, 0.f) + log1pf(__expf(-fabsf(xa)));
    rb.y = fmaxf(xb, 0.f) + log1pf(__expf(-fabsf(xb)));
    xa = fmaf(dltA, wd.z, bd.z); xb = fmaf(dltB, wd.z, bd.z);
    ra.z = fmaxf(xa, 0.f) + log1pf(__expf(-fabsf(xa)));
    rb.z = fmaxf(xb, 0.f) + log1pf(__expf(-fabsf(xb)));
    xa = fmaf(dltA, wd.w, bd.w); xb = fmaf(dltB, wd.w, bd.w);
    ra.w = fmaxf(xa, 0.f) + log1pf(__expf(-fabsf(xa)));
    rb.w = fmaxf(xb, 0.f) + log1pf(__expf(-fabsf(xb)));
    *(float4*)(xz + (size_t)rowA * (2 * DINNER) + d) = ra;
    *(float4*)(xz + (size_t)rowB * (2 * DINNER) + d) = rb;
  }
}

// ---------------------------------------------------------------------------
// Chunked scan, phase A. Lane = one (b, d, chunk); all 16 states in regs.
// ---------------------------------------------------------------------------
__global__ __launch_bounds__(256) void scanA(const float* __restrict__ u,
                                             const float* __restrict__ xz,
                                             const float* __restrict__ bc,
                                             const float* __restrict__ Amat,
                                             float* __restrict__ Pbuf,
                                             float* __restrict__ Wbuf) {
  const int tid  = threadIdx.x;
  const int dblk = blockIdx.x & 7;
  const int c    = (blockIdx.x >> 3) & (NCHUNK - 1);
  const int b    = blockIdx.x >> 8;
  const int d    = dblk * 256 + tid;
  const int t0   = c * LC;

  float A2[16];
  #pragma unroll
  for (int i = 0; i < 4; ++i) {
    float4 v = *(const float4*)(Amat + (size_t)d * 16 + i * 4);
    A2[i*4+0] = v.x * LOG2E; A2[i*4+1] = v.y * LOG2E;
    A2[i*4+2] = v.z * LOG2E; A2[i*4+3] = v.w * LOG2E;
  }
  float h[16];
  #pragma unroll
  for (int n = 0; n < 16; ++n) h[n] = 0.0f;
  float S = 0.0f;

  const float* bcb = bc + ((size_t)b * LSEQ + t0) * 32;
  size_t gu = ((size_t)b * LSEQ + t0) * DINNER + d;
  size_t gx = ((size_t)b * LSEQ + t0) * (2 * DINNER) + d;

  float u_c = u[gu], dl_c = xz[gx];
  for (int tt = 0; tt < LC; ++tt) {
    float u_n  = u [gu + DINNER];
    float dl_n = xz[gx + 2 * DINNER];
    gu += DINNER; gx += 2 * DINNER;
    float4 B0 = *(const float4*)(bcb + tt * 32 + 0);
    float4 B1 = *(const float4*)(bcb + tt * 32 + 4);
    float4 B2 = *(const float4*)(bcb + tt * 32 + 8);
    float4 B3 = *(const float4*)(bcb + tt * 32 + 12);
    float Bv[16] = {B0.x,B0.y,B0.z,B0.w, B1.x,B1.y,B1.z,B1.w,
                    B2.x,B2.y,B2.z,B2.w, B3.x,B3.y,B3.z,B3.w};
    S += dl_c;
    float dlu = dl_c * u_c;
    #pragma unroll
    for (int n = 0; n < 16; ++n) {
      float ab = exp2f(dl_c * A2[n]);
      h[n] = fmaf(ab, h[n], dlu * Bv[n]);
    }
    u_c = u_n; dl_c = dl_n;
  }

  size_t o = ((size_t)(b * DINNER + d) * NCHUNK + c) * 16;
  float P[16];
  #pragma unroll
  for (int n = 0; n < 16; ++n) P[n] = exp2f(A2[n] * S);
  #pragma unroll
  for (int i = 0; i < 4; ++i) {
    *(float4*)(Pbuf + o + i * 4) = make_float4(P[i*4], P[i*4+1], P[i*4+2], P[i*4+3]);
    *(float4*)(Wbuf + o + i * 4) = make_float4(h[i*4], h[i*4+1], h[i*4+2], h[i*4+3]);
  }
}

// ---------------------------------------------------------------------------
// Phase B: combine 32 chunk summaries per (b,d,n) lane; Hin over Pbuf.
// ---------------------------------------------------------------------------
__global__ __launch_bounds__(256) void scanB(float* __restrict__ Pbuf,
                                             const float* __restrict__ Wbuf) {
  const int lane_id = blockIdx.x * 256 + threadIdx.x;
  const int gc = lane_id >> 4;
  const int n  = lane_id & 15;
  const size_t base = (size_t)gc * NCHUNK * 16 + n;
  float P[NCHUNK], W[NCHUNK];
  #pragma unroll
  for (int c = 0; c < NCHUNK; ++c) {
    P[c] = Pbuf[base + (size_t)c * 16];
    W[c] = Wbuf[base + (size_t)c * 16];
  }
  float h = 0.0f;
  #pragma unroll
  for (int c = 0; c < NCHUNK; ++c) {
    float hin = h;
    h = P[c] * h + W[c];
    Pbuf[base + (size_t)c * 16] = hin;
  }
}

// ---------------------------------------------------------------------------
// Phase C: lane = one (b, d, chunk); rescan from Hin, y = sum_n h_n C_n,
// SiLU(z) gate, write y (fp32) in place over u.
// ---------------------------------------------------------------------------
__global__ __launch_bounds__(256) void scanC(float* __restrict__ u,
                                             const float* __restrict__ xz,
                                             const float* __restrict__ bc,
                                             const float* __restrict__ Amat,
                                             const float* __restrict__ Hin) {
  const int tid  = threadIdx.x;
  const int dblk = blockIdx.x & 7;
  const int c    = (blockIdx.x >> 3) & (NCHUNK - 1);
  const int b    = blockIdx.x >> 8;
  const int d    = dblk * 256 + tid;
  const int t0   = c * LC;

  float A2[16];
  #pragma unroll
  for (int i = 0; i < 4; ++i) {
    float4 v = *(const float4*)(Amat + (size_t)d * 16 + i * 4);
    A2[i*4+0] = v.x * LOG2E; A2[i*4+1] = v.y * LOG2E;
    A2[i*4+2] = v.z * LOG2E; A2[i*4+3] = v.w * LOG2E;
  }
  const size_t o = ((size_t)(b * DINNER + d) * NCHUNK + c) * 16;
  float h[16];
  #pragma unroll
  for (int i = 0; i < 4; ++i) {
    float4 v = *(const float4*)(Hin + o + i * 4);
    h[i*4+0] = v.x; h[i*4+1] = v.y; h[i*4+2] = v.z; h[i*4+3] = v.w;
  }

  const float* bcb = bc + ((size_t)b * LSEQ + t0) * 32;
  size_t gu = ((size_t)b * LSEQ + t0) * DINNER + d;
  size_t gx = ((size_t)b * LSEQ + t0) * (2 * DINNER) + d;

  float u_c = u[gu], dl_c = xz[gx], z_c = xz[gx + DINNER];
  for (int tt = 0; tt < LC; ++tt) {
    size_t cu = gu;
    gu += DINNER; gx += 2 * DINNER;
    float u_n  = u [gu];
    float dl_n = xz[gx];
    float z_n  = xz[gx + DINNER];
    float4 B0 = *(const float4*)(bcb + tt * 32 + 0);
    float4 B1 = *(const float4*)(bcb + tt * 32 + 4);
    float4 B2 = *(const float4*)(bcb + tt * 32 + 8);
    float4 B3 = *(const float4*)(bcb + tt * 32 + 12);
    float4 C0 = *(const float4*)(bcb + tt * 32 + 16);
    float4 C1 = *(const float4*)(bcb + tt * 32 + 20);
    float4 C2 = *(const float4*)(bcb + tt * 32 + 24);
    float4 C3 = *(const float4*)(bcb + tt * 32 + 28);
    float Bv[16] = {B0.x,B0.y,B0.z,B0.w, B1.x,B1.y,B1.z,B1.w,
                    B2.x,B2.y,B2.z,B2.w, B3.x,B3.y,B3.z,B3.w};
    float Cv[16] = {C0.x,C0.y,C0.z,C0.w, C1.x,C1.y,C1.z,C1.w,
                    C2.x,C2.y,C2.z,C2.w, C3.x,C3.y,C3.z,C3.w};
    float dlu = dl_c * u_c;
    float y = 0.0f;
    #pragma unroll
    for (int n = 0; n < 16; ++n) {
      float ab = exp2f(dl_c * A2[n]);
      h[n] = fmaf(ab, h[n], dlu * Bv[n]);
      y = fmaf(h[n], Cv[n], y);
    }
    float sig = 1.0f / (1.0f + __expf(-z_c));
    u[cu] = y * z_c * sig;
    u_c = u_n; dl_c = dl_n; z_c = z_n;
  }
}

// ---------------------------------------------------------------------------
extern "C" void kernel_launch(void* const* d_in, const int* in_sizes, int n_in,
                              void* d_out, int out_size, void* d_ws, size_t ws_size,
                              hipStream_t stream) {
  const float* x      = (const float*)d_in[0];
  const float* W_in   = (const float*)d_in[1];
  const float* conv_w = (const float*)d_in[2];
  const float* conv_b = (const float*)d_in[3];
  const float* A      = (const float*)d_in[4];
  const float* W_x    = (const float*)d_in[5];
  const float* W_dt   = (const float*)d_in[6];
  const float* b_dt   = (const float*)d_in[7];
  const float* W_out  = (const float*)d_in[8];
  float* out = (float*)d_out;

  float* ws = (float*)d_ws;
  float* xz = ws;                                        // (B*L, 4096)   64 MB
  float* u  = xz + (size_t)BATCH * LSEQ * 2 * DINNER;    // (B*L, 2048)   32 MB
  float* bc = u  + (size_t)BATCH * LSEQ * DINNER;        // (B*L, 32)    0.5 MB
  float* Pb = bc + (size_t)BATCH * LSEQ * 32;            // 2M floats      8 MB
  float* Wb = Pb + (size_t)BATCH * DINNER * NCHUNK * 16; // 2M floats      8 MB

  const int ML = BATCH * LSEQ;  // 4096

  // bf16 aliases (regions dead at time of use)
  unsigned short* x_bf    = (unsigned short*)Pb;   // dead until scanA
  unsigned short* win_bf  = (unsigned short*)Wb;   // dead until scanA
  unsigned short* y_bf    = (unsigned short*)Pb;   // spans Pb+Wb, dead after scanC
  unsigned short* wout_bf = (unsigned short*)xz;   // xz dead after scanC

  // 0) convert in_proj operands to bf16
  cvt_bf16<<<(ML * DMODEL / 4) / 256, 256, 0, stream>>>((const float4*)x,    (ushort4*)x_bf,   ML * DMODEL / 4);
  cvt_bf16<<<(2 * DINNER * DMODEL / 4) / 256, 256, 0, stream>>>((const float4*)W_in, (ushort4*)win_bf, 2 * DINNER * DMODEL / 4);
  // 1) in_proj (bf16 MFMA)
  gemm_bf16<2 * DINNER, DMODEL><<<dim3((2 * DINNER) / 128, ML / 128), 256, 0, stream>>>(x_bf, win_bf, xz);
  // 2) conv + silu
  conv_kernel<<<(ML * DINNER / 4) / 256, 256, 0, stream>>>(xz, conv_w, conv_b, u);
  // 3) x_dbl (LDS-staged Wx, fp32-exact)
  xdbl_kernel<<<ML / 8, 256, 0, stream>>>(u, W_x, W_dt, b_dt, xz, bc);
  // 4) chunked selective scan (register-state lanes)
  scanA<<<BATCH * NCHUNK * 8, 256, 0, stream>>>(u, xz, bc, A, Pb, Wb);
  scanB<<<(BATCH * DINNER * NST) / 256, 256, 0, stream>>>(Pb, Wb);
  scanC<<<BATCH * NCHUNK * 8, 256, 0, stream>>>(u, xz, bc, A, Pb);
  // 5) convert out_proj operands, then out_proj (bf16 MFMA)
  cvt_bf16<<<(ML * DINNER / 4) / 256, 256, 0, stream>>>((const float4*)u,     (ushort4*)y_bf,    ML * DINNER / 4);
  cvt_bf16<<<(DMODEL * DINNER / 4) / 256, 256, 0, stream>>>((const float4*)W_out, (ushort4*)wout_bf, DMODEL * DINNER / 4);
  gemm_bf16<DMODEL, DINNER><<<dim3(DMODEL / 128, ML / 128), 256, 0, stream>>>(y_bf, wout_bf, out);
}

// Round 7
// 257.043 us; speedup vs baseline: 1.3126x; 1.2383x over previous
//
#include <hip/hip_runtime.h>
#include <hip/hip_bf16.h>

// Problem constants
#define BATCH   2
#define LSEQ    2048
#define DMODEL  1024
#define DINNER  2048
#define NST     16

// Chunked scan parameters
#define LC      64
#define NCHUNK  (LSEQ / LC)   // 32

#define LOG2E 1.4426950408889634f

typedef __bf16 bf16x8 __attribute__((ext_vector_type(8)));
typedef float  f32x4  __attribute__((ext_vector_type(4)));

// float -> bf16 round-to-nearest-even (inputs are finite; skip NaN path)
__device__ __forceinline__ unsigned short f2bf(float f) {
  unsigned int u = __float_as_uint(f);
  return (unsigned short)((u + 0x7FFFu + ((u >> 16) & 1u)) >> 16);
}

// raw v_exp_f32 (2^x). Inputs here are small-magnitude — no range fixup needed.
__device__ __forceinline__ float fast_exp2(float x) {
#if __has_builtin(__builtin_amdgcn_exp2f)
  return __builtin_amdgcn_exp2f(x);
#else
  float r; asm("v_exp_f32 %0, %1\ns_nop 0" : "=v"(r) : "v"(x)); return r;
#endif
}

__device__ __forceinline__ void async_copy16(const void* g, void* l) {
  __builtin_amdgcn_global_load_lds((__attribute__((address_space(1))) void*)g,
                                   (__attribute__((address_space(3))) void*)l,
                                   16, 0, 0);
}

// ---------------------------------------------------------------------------
// f32 -> bf16 conversion, 4 elements/thread
// ---------------------------------------------------------------------------
__global__ __launch_bounds__(256) void cvt_bf16(const float4* __restrict__ in,
                                                ushort4* __restrict__ o, int n4) {
  int i = blockIdx.x * 256 + threadIdx.x;
  if (i >= n4) return;
  float4 v = in[i];
  ushort4 r;
  r.x = f2bf(v.x); r.y = f2bf(v.y); r.z = f2bf(v.z); r.w = f2bf(v.w);
  o[i] = r;
}

// ---------------------------------------------------------------------------
// bf16 NT GEMM (m97 structure): C[m][n] = sum_k A[m][k]*B[n][k], C fp32.
// ---------------------------------------------------------------------------
template<int N, int K>
__global__ __launch_bounds__(256, 2) void gemm_bf16(const unsigned short* __restrict__ A,
                                                    const unsigned short* __restrict__ B,
                                                    float* __restrict__ C) {
  __shared__ unsigned short As[128][32];
  __shared__ unsigned short Bs[128][32];
  const int tid  = threadIdx.x;
  const int wave = tid >> 6;
  const int lane = tid & 63;
  const int row0 = blockIdx.y * 128;
  const int col0 = blockIdx.x * 128;
  const int wr   = (wave >> 1) * 64;
  const int wc   = (wave & 1)  * 64;
  const int fr   = lane & 15;
  const int fq   = lane >> 4;

  f32x4 acc[4][4] = {};

  const int srow = tid >> 2;
  const int skof = (tid & 3) * 8;
  const unsigned short* gA = A + (size_t)(row0 + srow) * K + skof;
  const unsigned short* gB = B + (size_t)(col0 + srow) * K + skof;
  char* lA = (char*)&As[0][0] + wave * 1024;
  char* lB = (char*)&Bs[0][0] + wave * 1024;

  for (int k0 = 0; k0 < K; k0 += 32) {
    async_copy16(gA + k0,          lA);
    async_copy16(gA + k0 + 64 * K, lA + 4096);
    async_copy16(gB + k0,          lB);
    async_copy16(gB + k0 + 64 * K, lB + 4096);
    __syncthreads();

    bf16x8 af[4], bfr[4];
    #pragma unroll
    for (int i = 0; i < 4; ++i) {
      af[i]  = *(const bf16x8*)((const char*)&As[0][0] + (wr + i * 16 + fr) * 64 + fq * 16);
      bfr[i] = *(const bf16x8*)((const char*)&Bs[0][0] + (wc + i * 16 + fr) * 64 + fq * 16);
    }
    #pragma unroll
    for (int i = 0; i < 4; ++i)
      #pragma unroll
      for (int j = 0; j < 4; ++j)
        acc[i][j] = __builtin_amdgcn_mfma_f32_16x16x32_bf16(af[i], bfr[j], acc[i][j], 0, 0, 0);
    __syncthreads();
  }

  #pragma unroll
  for (int i = 0; i < 4; ++i)
    #pragma unroll
    for (int j = 0; j < 4; ++j) {
      int row = row0 + wr + i * 16 + fq * 4;
      int col = col0 + wc + j * 16 + fr;
      #pragma unroll
      for (int r = 0; r < 4; ++r)
        C[(size_t)(row + r) * N + col] = acc[i][j][r];
    }
}

// ---------------------------------------------------------------------------
// Causal depthwise conv1d(K=4) + bias + SiLU, 4 d-channels per thread.
// ---------------------------------------------------------------------------
__global__ __launch_bounds__(256) void conv_kernel(const float* __restrict__ xz,
                                                   const float* __restrict__ cw,
                                                   const float* __restrict__ cb,
                                                   float* __restrict__ u) {
  size_t i4 = (size_t)blockIdx.x * 256 + threadIdx.x;  // float4 index over B*L*D/4
  int d4 = (int)(i4 & (DINNER / 4 - 1));
  int t  = (int)((i4 >> 9) & (LSEQ - 1));
  int d  = d4 * 4;

  float4 w0 = *(const float4*)(cw + (d + 0) * 4);
  float4 w1 = *(const float4*)(cw + (d + 1) * 4);
  float4 w2 = *(const float4*)(cw + (d + 2) * 4);
  float4 w3 = *(const float4*)(cw + (d + 3) * 4);
  float4 bias = *(const float4*)(cb + d);

  size_t base = i4 * 8 - (size_t)d;  // row*2*DINNER + d, row = b*L+t
  const float4 zero = make_float4(0.f, 0.f, 0.f, 0.f);
  float4 x0 =          *(const float4*)(xz + base);
  float4 x1 = (t >= 1) ? *(const float4*)(xz + base - 1 * (2 * DINNER)) : zero;
  float4 x2 = (t >= 2) ? *(const float4*)(xz + base - 2 * (2 * DINNER)) : zero;
  float4 x3 = (t >= 3) ? *(const float4*)(xz + base - 3 * (2 * DINNER)) : zero;

  float4 s;
  s.x = bias.x + w0.x * x3.x + w0.y * x2.x + w0.z * x1.x + w0.w * x0.x;
  s.y = bias.y + w1.x * x3.y + w1.y * x2.y + w1.z * x1.y + w1.w * x0.y;
  s.z = bias.z + w2.x * x3.z + w2.y * x2.z + w2.z * x1.z + w2.w * x0.z;
  s.w = bias.w + w3.x * x3.w + w3.y * x2.w + w3.z * x1.w + w3.w * x0.w;

  float4 r;
  r.x = s.x / (1.0f + __expf(-s.x));
  r.y = s.y / (1.0f + __expf(-s.y));
  r.z = s.z / (1.0f + __expf(-s.z));
  r.w = s.w / (1.0f + __expf(-s.w));
  *(float4*)(u + i4 * 4) = r;
}

// ---------------------------------------------------------------------------
// x_dbl: one wave per 2 rows (4 waves/block -> 8 rows/block, 512 blocks).
// Wx staged in LDS per 256-wide k-tile via global_load_lds. fp32-exact.
// ---------------------------------------------------------------------------
__global__ __launch_bounds__(256) void xdbl_kernel(const float* __restrict__ u,
                                                   const float* __restrict__ Wx,
                                                   const float* __restrict__ Wdt,
                                                   const float* __restrict__ bdt,
                                                   float* __restrict__ xz,
                                                   float* __restrict__ bc) {
  __shared__ float sW[33 * 256];   // 33.8 KB: Wx tile [e=0..32][k0..k0+255]
  const int tid  = threadIdx.x;
  const int wave = tid >> 6;
  const int lane = tid & 63;
  const int rowA = blockIdx.x * 8 + wave * 2;
  const int rowB = rowA + 1;

  float accA[33], accB[33];
  #pragma unroll
  for (int e = 0; e < 33; ++e) { accA[e] = 0.0f; accB[e] = 0.0f; }

  const float* uA = u + (size_t)rowA * DINNER;
  const float* uB = u + (size_t)rowB * DINNER;

  for (int k0 = 0; k0 < DINNER; k0 += 256) {
    #pragma unroll
    for (int j = 0; j < 9; ++j) {
      int i = j * 256 + wave * 64 + lane;   // transfer index
      if (i < 33 * 64) {                    // wave-uniform predicate
        int e = i >> 6;
        int c = (i & 63) * 4;
        async_copy16(Wx + (size_t)e * DINNER + k0 + c,
                     (char*)sW + (size_t)(j * 256 + wave * 64) * 16);
      }
    }
    __syncthreads();   // drains vmcnt: tile resident

    float4 a4 = *(const float4*)(uA + k0 + lane * 4);
    float4 b4 = *(const float4*)(uB + k0 + lane * 4);
    #pragma unroll
    for (int e = 0; e < 33; ++e) {
      float4 w = *(const float4*)(sW + e * 256 + lane * 4);  // ds_read_b128
      accA[e] = fmaf(a4.x, w.x, fmaf(a4.y, w.y, fmaf(a4.z, w.z, fmaf(a4.w, w.w, accA[e]))));
      accB[e] = fmaf(b4.x, w.x, fmaf(b4.y, w.y, fmaf(b4.z, w.z, fmaf(b4.w, w.w, accB[e]))));
    }
    __syncthreads();   // reads done before next stage overwrites
  }

  #pragma unroll
  for (int e = 0; e < 33; ++e) {
    #pragma unroll
    for (int m = 1; m < 64; m <<= 1) {
      accA[e] += __shfl_xor(accA[e], m);
      accB[e] += __shfl_xor(accB[e], m);
    }
  }

  if (lane == 0) {
    #pragma unroll
    for (int e = 1; e < 33; ++e) bc[(size_t)rowA * 32 + e - 1] = accA[e];
  } else if (lane == 1) {
    #pragma unroll
    for (int e = 1; e < 33; ++e) bc[(size_t)rowB * 32 + e - 1] = accB[e];
  }

  const float dltA = accA[0];
  const float dltB = accB[0];
  #pragma unroll
  for (int i = 0; i < 8; ++i) {
    const int d = (i * 64 + lane) * 4;
    float4 wd = *(const float4*)(Wdt + d);
    float4 bd = *(const float4*)(bdt + d);
    float4 ra, rb;
    float xa, xb;
    xa = fmaf(dltA, wd.x, bd.x); xb = fmaf(dltB, wd.x, bd.x);
    ra.x = fmaxf(xa, 0.f) + log1pf(__expf(-fabsf(xa)));
    rb.x = fmaxf(xb, 0.f) + log1pf(__expf(-fabsf(xb)));
    xa = fmaf(dltA, wd.y, bd.y); xb = fmaf(dltB, wd.y, bd.y);
    ra.y = fmaxf(xa, 0.f) + log1pf(__expf(-fabsf(xa)));
    rb.y = fmaxf(xb, 0.f) + log1pf(__expf(-fabsf(xb)));
    xa = fmaf(dltA, wd.z, bd.z); xb = fmaf(dltB, wd.z, bd.z);
    ra.z = fmaxf(xa, 0.f) + log1pf(__expf(-fabsf(xa)));
    rb.z = fmaxf(xb, 0.f) + log1pf(__expf(-fabsf(xb)));
    xa = fmaf(dltA, wd.w, bd.w); xb = fmaf(dltB, wd.w, bd.w);
    ra.w = fmaxf(xa, 0.f) + log1pf(__expf(-fabsf(xa)));
    rb.w = fmaxf(xb, 0.f) + log1pf(__expf(-fabsf(xb)));
    *(float4*)(xz + (size_t)rowA * (2 * DINNER) + d) = ra;
    *(float4*)(xz + (size_t)rowB * (2 * DINNER) + d) = rb;
  }
}

// ---------------------------------------------------------------------------
// Chunked scan, phase A. Lane = one (b, d, chunk); 16 states in regs.
// bc B-half staged in LDS; u/dl streams depth-2 pipelined; native v_exp.
// ---------------------------------------------------------------------------
__global__ __launch_bounds__(256) void scanA(const float* __restrict__ u,
                                             const float* __restrict__ xz,
                                             const float* __restrict__ bc,
                                             const float* __restrict__ Amat,
                                             float* __restrict__ Pbuf,
                                             float* __restrict__ Wbuf) {
  __shared__ float sB[LC][16];   // 4 KB
  const int tid  = threadIdx.x;
  const int dblk = blockIdx.x & 7;
  const int c    = (blockIdx.x >> 3) & (NCHUNK - 1);
  const int b    = blockIdx.x >> 8;
  const int d    = dblk * 256 + tid;
  const int t0   = c * LC;

  // stage B-half of bc: 64 rows x 16 floats = 256 float4, one per thread
  {
    int r = tid >> 2, cp = (tid & 3) * 4;
    *(float4*)&sB[r][cp] = *(const float4*)(bc + ((size_t)(b * LSEQ + t0) + r) * 32 + cp);
  }

  float A2[16];
  #pragma unroll
  for (int i = 0; i < 4; ++i) {
    float4 v = *(const float4*)(Amat + (size_t)d * 16 + i * 4);
    A2[i*4+0] = v.x * LOG2E; A2[i*4+1] = v.y * LOG2E;
    A2[i*4+2] = v.z * LOG2E; A2[i*4+3] = v.w * LOG2E;
  }
  float h[16];
  #pragma unroll
  for (int n = 0; n < 16; ++n) h[n] = 0.0f;
  float S = 0.0f;

  size_t gu = ((size_t)b * LSEQ + t0) * DINNER + d;
  size_t gx = ((size_t)b * LSEQ + t0) * (2 * DINNER) + d;

  float u0 = u[gu],          u1  = u[gu + DINNER];
  float dl0 = xz[gx],        dl1 = xz[gx + 2 * DINNER];
  __syncthreads();

  auto body = [&](float uc, float dlc, int ttl) {
    float Bv[16];
    *(float4*)&Bv[0]  = *(const float4*)&sB[ttl][0];
    *(float4*)&Bv[4]  = *(const float4*)&sB[ttl][4];
    *(float4*)&Bv[8]  = *(const float4*)&sB[ttl][8];
    *(float4*)&Bv[12] = *(const float4*)&sB[ttl][12];
    S += dlc;
    float dlu = dlc * uc;
    #pragma unroll
    for (int n = 0; n < 16; ++n) {
      float ab = fast_exp2(dlc * A2[n]);
      h[n] = fmaf(ab, h[n], dlu * Bv[n]);
    }
  };

  for (int tt = 0; tt < LC; tt += 2) {
    // prefetch t+2, t+3 (tail over-read stays inside d_ws; values unused)
    float u2  = u[gu + 2 * DINNER], u3  = u[gu + 3 * DINNER];
    float dl2 = xz[gx + 4 * DINNER], dl3 = xz[gx + 6 * DINNER];
    body(u0, dl0, tt);
    body(u1, dl1, tt + 1);
    u0 = u2; u1 = u3; dl0 = dl2; dl1 = dl3;
    gu += 2 * DINNER; gx += 4 * DINNER;
  }

  size_t o = ((size_t)(b * DINNER + d) * NCHUNK + c) * 16;
  float P[16];
  #pragma unroll
  for (int n = 0; n < 16; ++n) P[n] = fast_exp2(A2[n] * S);
  #pragma unroll
  for (int i = 0; i < 4; ++i) {
    *(float4*)(Pbuf + o + i * 4) = make_float4(P[i*4], P[i*4+1], P[i*4+2], P[i*4+3]);
    *(float4*)(Wbuf + o + i * 4) = make_float4(h[i*4], h[i*4+1], h[i*4+2], h[i*4+3]);
  }
}

// ---------------------------------------------------------------------------
// Phase B: combine 32 chunk summaries per (b,d,n) lane; Hin over Pbuf.
// ---------------------------------------------------------------------------
__global__ __launch_bounds__(256) void scanB(float* __restrict__ Pbuf,
                                             const float* __restrict__ Wbuf) {
  const int lane_id = blockIdx.x * 256 + threadIdx.x;
  const int gc = lane_id >> 4;
  const int n  = lane_id & 15;
  const size_t base = (size_t)gc * NCHUNK * 16 + n;
  float P[NCHUNK], W[NCHUNK];
  #pragma unroll
  for (int c = 0; c < NCHUNK; ++c) {
    P[c] = Pbuf[base + (size_t)c * 16];
    W[c] = Wbuf[base + (size_t)c * 16];
  }
  float h = 0.0f;
  #pragma unroll
  for (int c = 0; c < NCHUNK; ++c) {
    float hin = h;
    h = P[c] * h + W[c];
    Pbuf[base + (size_t)c * 16] = hin;
  }
}

// ---------------------------------------------------------------------------
// Phase C: lane = one (b, d, chunk); rescan from Hin, y = sum_n h_n C_n,
// SiLU(z) gate, write y in place over u. bc staged in LDS; depth-2 pipeline.
// ---------------------------------------------------------------------------
__global__ __launch_bounds__(256) void scanC(float* __restrict__ u,
                                             const float* __restrict__ xz,
                                             const float* __restrict__ bc,
                                             const float* __restrict__ Amat,
                                             const float* __restrict__ Hin) {
  __shared__ float sbc[LC][32];  // 8 KB
  const int tid  = threadIdx.x;
  const int dblk = blockIdx.x & 7;
  const int c    = (blockIdx.x >> 3) & (NCHUNK - 1);
  const int b    = blockIdx.x >> 8;
  const int d    = dblk * 256 + tid;
  const int t0   = c * LC;

  // stage full bc chunk: 64 rows x 32 floats = 512 float4, 2 per thread
  {
    const float4* src = (const float4*)(bc + ((size_t)b * LSEQ + t0) * 32);
    ((float4*)sbc)[tid]       = src[tid];
    ((float4*)sbc)[tid + 256] = src[tid + 256];
  }

  float A2[16];
  #pragma unroll
  for (int i = 0; i < 4; ++i) {
    float4 v = *(const float4*)(Amat + (size_t)d * 16 + i * 4);
    A2[i*4+0] = v.x * LOG2E; A2[i*4+1] = v.y * LOG2E;
    A2[i*4+2] = v.z * LOG2E; A2[i*4+3] = v.w * LOG2E;
  }
  const size_t o = ((size_t)(b * DINNER + d) * NCHUNK + c) * 16;
  float h[16];
  #pragma unroll
  for (int i = 0; i < 4; ++i) {
    float4 v = *(const float4*)(Hin + o + i * 4);
    h[i*4+0] = v.x; h[i*4+1] = v.y; h[i*4+2] = v.z; h[i*4+3] = v.w;
  }

  size_t gu = ((size_t)b * LSEQ + t0) * DINNER + d;
  size_t gx = ((size_t)b * LSEQ + t0) * (2 * DINNER) + d;

  float u0 = u[gu],              u1 = u[gu + DINNER];
  float dl0 = xz[gx],            dl1 = xz[gx + 2 * DINNER];
  float z0 = xz[gx + DINNER],    z1 = xz[gx + 3 * DINNER];
  __syncthreads();

  auto body = [&](float uc, float dlc, float zc, int ttl, size_t cu) {
    float Bv[16], Cv[16];
    *(float4*)&Bv[0]  = *(const float4*)&sbc[ttl][0];
    *(float4*)&Bv[4]  = *(const float4*)&sbc[ttl][4];
    *(float4*)&Bv[8]  = *(const float4*)&sbc[ttl][8];
    *(float4*)&Bv[12] = *(const float4*)&sbc[ttl][12];
    *(float4*)&Cv[0]  = *(const float4*)&sbc[ttl][16];
    *(float4*)&Cv[4]  = *(const float4*)&sbc[ttl][20];
    *(float4*)&Cv[8]  = *(const float4*)&sbc[ttl][24];
    *(float4*)&Cv[12] = *(const float4*)&sbc[ttl][28];
    float dlu = dlc * uc;
    float y = 0.0f;
    #pragma unroll
    for (int n = 0; n < 16; ++n) {
      float ab = fast_exp2(dlc * A2[n]);
      h[n] = fmaf(ab, h[n], dlu * Bv[n]);
      y = fmaf(h[n], Cv[n], y);
    }
    float sig = 1.0f / (1.0f + __expf(-zc));
    u[cu] = y * zc * sig;
  };

  for (int tt = 0; tt < LC; tt += 2) {
    float u2  = u[gu + 2 * DINNER],  u3  = u[gu + 3 * DINNER];
    float dl2 = xz[gx + 4 * DINNER], dl3 = xz[gx + 6 * DINNER];
    float z2  = xz[gx + 5 * DINNER], z3  = xz[gx + 7 * DINNER];
    body(u0, dl0, z0, tt,     gu);
    body(u1, dl1, z1, tt + 1, gu + DINNER);
    u0 = u2; u1 = u3; dl0 = dl2; dl1 = dl3; z0 = z2; z1 = z3;
    gu += 2 * DINNER; gx += 4 * DINNER;
  }
}

// ---------------------------------------------------------------------------
extern "C" void kernel_launch(void* const* d_in, const int* in_sizes, int n_in,
                              void* d_out, int out_size, void* d_ws, size_t ws_size,
                              hipStream_t stream) {
  const float* x      = (const float*)d_in[0];
  const float* W_in   = (const float*)d_in[1];
  const float* conv_w = (const float*)d_in[2];
  const float* conv_b = (const float*)d_in[3];
  const float* A      = (const float*)d_in[4];
  const float* W_x    = (const float*)d_in[5];
  const float* W_dt   = (const float*)d_in[6];
  const float* b_dt   = (const float*)d_in[7];
  const float* W_out  = (const float*)d_in[8];
  float* out = (float*)d_out;

  float* ws = (float*)d_ws;
  float* xz = ws;                                        // (B*L, 4096)   64 MB
  float* u  = xz + (size_t)BATCH * LSEQ * 2 * DINNER;    // (B*L, 2048)   32 MB
  float* bc = u  + (size_t)BATCH * LSEQ * DINNER;        // (B*L, 32)    0.5 MB
  float* Pb = bc + (size_t)BATCH * LSEQ * 32;            // 2M floats      8 MB
  float* Wb = Pb + (size_t)BATCH * DINNER * NCHUNK * 16; // 2M floats      8 MB

  const int ML = BATCH * LSEQ;  // 4096

  // bf16 aliases (regions dead at time of use)
  unsigned short* x_bf    = (unsigned short*)Pb;   // dead until scanA
  unsigned short* win_bf  = (unsigned short*)Wb;   // dead until scanA
  unsigned short* y_bf    = (unsigned short*)Pb;   // spans Pb+Wb, dead after scanC
  unsigned short* wout_bf = (unsigned short*)xz;   // xz dead after scanC

  // 0) convert in_proj operands to bf16
  cvt_bf16<<<(ML * DMODEL / 4) / 256, 256, 0, stream>>>((const float4*)x,    (ushort4*)x_bf,   ML * DMODEL / 4);
  cvt_bf16<<<(2 * DINNER * DMODEL / 4) / 256, 256, 0, stream>>>((const float4*)W_in, (ushort4*)win_bf, 2 * DINNER * DMODEL / 4);
  // 1) in_proj (bf16 MFMA)
  gemm_bf16<2 * DINNER, DMODEL><<<dim3((2 * DINNER) / 128, ML / 128), 256, 0, stream>>>(x_bf, win_bf, xz);
  // 2) conv + silu
  conv_kernel<<<(ML * DINNER / 4) / 256, 256, 0, stream>>>(xz, conv_w, conv_b, u);
  // 3) x_dbl (LDS-staged Wx, fp32-exact)
  xdbl_kernel<<<ML / 8, 256, 0, stream>>>(u, W_x, W_dt, b_dt, xz, bc);
  // 4) chunked selective scan (register-state lanes)
  scanA<<<BATCH * NCHUNK * 8, 256, 0, stream>>>(u, xz, bc, A, Pb, Wb);
  scanB<<<(BATCH * DINNER * NST) / 256, 256, 0, stream>>>(Pb, Wb);
  scanC<<<BATCH * NCHUNK * 8, 256, 0, stream>>>(u, xz, bc, A, Pb);
  // 5) convert out_proj operands, then out_proj (bf16 MFMA)
  cvt_bf16<<<(ML * DINNER / 4) / 256, 256, 0, stream>>>((const float4*)u,     (ushort4*)y_bf,    ML * DINNER / 4);
  cvt_bf16<<<(DMODEL * DINNER / 4) / 256, 256, 0, stream>>>((const float4*)W_out, (ushort4*)wout_bf, DMODEL * DINNER / 4);
  gemm_bf16<DMODEL, DINNER><<<dim3(DMODEL / 128, ML / 128), 256, 0, stream>>>(y_bf, wout_bf, out);
}